// Round 4
// baseline (1797.178 us; speedup 1.0000x reference)
//
#include <hip/hip_runtime.h>
#include <math.h>

#define M_PTS 29696
#define KCL 100
#define NZ_DIM 32

typedef _Float16 h8 __attribute__((ext_vector_type(8)));
typedef _Float16 h4 __attribute__((ext_vector_type(4)));
typedef float f4 __attribute__((ext_vector_type(4)));

// async global->LDS, 16B per lane; LDS dest is wave-uniform base + lane*16
__device__ __forceinline__ void load_lds16(const void* g, void* l) {
    __builtin_amdgcn_global_load_lds(
        (const __attribute__((address_space(1))) void*)g,
        (__attribute__((address_space(3))) void*)l, 16, 0, 0);
}

// ---------------- weight transpose+split: W (KxN) fp32 -> WTh/WTl (NxK) f16 ----------------
__global__ __launch_bounds__(256)
void transpose_split(const float* __restrict__ W, _Float16* __restrict__ WTh,
                     _Float16* __restrict__ WTl, int K, int N)
{
    __shared__ float t[32][33];
    const int tid = threadIdx.x;
    const int n0 = blockIdx.x * 32, k0 = blockIdx.y * 32;
    {
        int r = tid / 8, c = (tid % 8) * 4;
        const float4 v = *(const float4*)(W + (size_t)(k0 + r) * N + n0 + c);
        t[r][c+0] = v.x; t[r][c+1] = v.y; t[r][c+2] = v.z; t[r][c+3] = v.w;
    }
    __syncthreads();
    {
        int r = tid / 8, c = (tid % 8) * 4;   // r = n idx, c = k idx
        h4 hi, lo;
        #pragma unroll
        for (int u = 0; u < 4; ++u) {
            float f = t[c+u][r];
            _Float16 h = (_Float16)f;
            hi[u] = h; lo[u] = (_Float16)(f - (float)h);
        }
        *(h4*)(WTh + (size_t)(n0 + r) * K + k0 + c) = hi;
        *(h4*)(WTl + (size_t)(n0 + r) * K + k0 + c) = lo;
    }
}

// ---------------- x split: fp32 -> hi/lo f16 planes ----------------
__global__ __launch_bounds__(256)
void split_x_kernel(const float* __restrict__ x, _Float16* __restrict__ Xh,
                    _Float16* __restrict__ Xl)
{
    const size_t i = ((size_t)blockIdx.x*256 + threadIdx.x)*4;
    const float4 v = *(const float4*)(x + i);
    float vv[4] = {v.x, v.y, v.z, v.w};
    h4 hi, lo;
    #pragma unroll
    for (int u = 0; u < 4; ++u) {
        _Float16 h = (_Float16)vv[u];
        hi[u] = h; lo[u] = (_Float16)(vv[u] - (float)h);
    }
    *(h4*)(Xh + i) = hi;
    *(h4*)(Xl + i) = lo;
}

// ---------------- MFMA GEMM on pre-split f16 planes ----------------
// A planes: MxK; B planes: NxK. C = act(A@B^T + bias).
// MODE 0: write hi/lo planes. MODE 1: planes + fp32. MODE 2: fused re-loss vs Xref.
template<int WM,int WN,int TM,int TN,bool RELU,int MODE>
__global__ __launch_bounds__(WM*WN*64)
void gemm_sp(const _Float16* __restrict__ Ahp, const _Float16* __restrict__ Alp,
             const _Float16* __restrict__ Bhp, const _Float16* __restrict__ Blp,
             const float* __restrict__ bias,
             _Float16* __restrict__ Ch, _Float16* __restrict__ Cl,
             float* __restrict__ Cf, const float* __restrict__ Xref,
             double* __restrict__ loss_acc,
             int M, int N, int K)
{
    constexpr int BM = WM*TM*16, BN = WN*TN*16, NW = WM*WN;
    constexpr int CA = BM/16, CB = BN/16;   // 1KB chunks per plane
    __shared__ __align__(16) _Float16 AhS[BM*32];
    __shared__ __align__(16) _Float16 AlS[BM*32];
    __shared__ __align__(16) _Float16 BhS[BN*32];
    __shared__ __align__(16) _Float16 BlS[BN*32];

    const int tid = threadIdx.x;
    const int wave = tid >> 6, lane = tid & 63;
    const int wm = wave / WN, wn = wave % WN;
    const int lrow = lane & 15, lq = lane >> 4;
    const int sw = (lrow >> 1) & 3;         // fragment-read bank swizzle
    const int lr4 = lane >> 2, lc4 = lane & 3;  // staging: row-in-chunk, 16B col
    const int bm0 = blockIdx.y * BM, bn0 = blockIdx.x * BN;

    f4 acc[TM][TN];
    #pragma unroll
    for (int i = 0; i < TM; ++i)
        #pragma unroll
        for (int j = 0; j < TN; ++j)
            acc[i][j] = (f4)0.0f;

    for (int k0 = 0; k0 < K; k0 += 32) {
        __syncthreads();
        // ---- async stage A/B tiles; swizzled source chunk = cq ^ ((row>>1)&3) ----
        #pragma unroll
        for (int c = wave; c < CA; c += NW) {
            int r = c*16 + lr4;
            int g = lc4 ^ ((r >> 1) & 3);
            size_t goff = (size_t)(bm0 + r)*K + k0 + g*8;
            load_lds16(Ahp + goff, (char*)AhS + c*1024);
            load_lds16(Alp + goff, (char*)AlS + c*1024);
        }
        #pragma unroll
        for (int c = wave; c < CB; c += NW) {
            int r = c*16 + lr4;
            int g = lc4 ^ ((r >> 1) & 3);
            size_t goff = (size_t)(bn0 + r)*K + k0 + g*8;
            load_lds16(Bhp + goff, (char*)BhS + c*1024);
            load_lds16(Blp + goff, (char*)BlS + c*1024);
        }
        __syncthreads();
        // ---- fragments (swizzle-aware) ----
        h8 ah[TM], al[TM], bh[TN], bl[TN];
        #pragma unroll
        for (int i = 0; i < TM; ++i) {
            int row = (wm*TM + i)*16 + lrow;
            int off = row*32 + ((lq ^ sw)*8);
            ah[i] = *(const h8*)(AhS + off);
            al[i] = *(const h8*)(AlS + off);
        }
        #pragma unroll
        for (int j = 0; j < TN; ++j) {
            int row = (wn*TN + j)*16 + lrow;
            int off = row*32 + ((lq ^ sw)*8);
            bh[j] = *(const h8*)(BhS + off);
            bl[j] = *(const h8*)(BlS + off);
        }
        // ---- 3-term split-precision MFMA ----
        #pragma unroll
        for (int i = 0; i < TM; ++i)
            #pragma unroll
            for (int j = 0; j < TN; ++j)
                acc[i][j] = __builtin_amdgcn_mfma_f32_16x16x32_f16(ah[i], bh[j], acc[i][j], 0, 0, 0);
        #pragma unroll
        for (int i = 0; i < TM; ++i)
            #pragma unroll
            for (int j = 0; j < TN; ++j)
                acc[i][j] = __builtin_amdgcn_mfma_f32_16x16x32_f16(ah[i], bl[j], acc[i][j], 0, 0, 0);
        #pragma unroll
        for (int i = 0; i < TM; ++i)
            #pragma unroll
            for (int j = 0; j < TN; ++j)
                acc[i][j] = __builtin_amdgcn_mfma_f32_16x16x32_f16(al[i], bh[j], acc[i][j], 0, 0, 0);
    }

    // ---- epilogue ----
    float lsum = 0.0f;
    #pragma unroll
    for (int j = 0; j < TN; ++j) {
        int col = bn0 + (wn*TN + j)*16 + lrow;
        float bj = bias[col];
        #pragma unroll
        for (int i = 0; i < TM; ++i) {
            int rbase = bm0 + (wm*TM + i)*16 + lq*4;
            #pragma unroll
            for (int r = 0; r < 4; ++r) {
                float v = acc[i][j][r] + bj;
                if (RELU) v = fmaxf(v, 0.0f);
                size_t idx = (size_t)(rbase + r)*N + col;
                if (MODE == 2) {
                    float d = v - Xref[idx];
                    lsum = fmaf(d, d, lsum);
                } else {
                    _Float16 hh = (_Float16)v;
                    __builtin_nontemporal_store(hh, &Ch[idx]);
                    __builtin_nontemporal_store((_Float16)(v - (float)hh), &Cl[idx]);
                    if (MODE == 1) __builtin_nontemporal_store(v, &Cf[idx]);
                }
            }
        }
    }
    if (MODE == 2) {
        for (int off = 32; off > 0; off >>= 1) lsum += __shfl_down(lsum, off, 64);
        __syncthreads();
        float* sc = (float*)AhS;
        if (lane == 0) sc[wave] = lsum;
        __syncthreads();
        if (tid == 0) {
            double t = 0.0;
            for (int w = 0; w < NW; ++w) t += (double)sc[w];
            atomicAdd(loss_acc, t);
        }
    }
}

// ---------------- accumulator zeroing ----------------
__global__ void zero_acc(float* __restrict__ u, int* __restrict__ cnt, double* __restrict__ dbl)
{
    int t = threadIdx.x;
    if (t < KCL) { u[t] = 0.0f; cnt[t] = 0; }
    if (t < 8) dbl[t] = 0.0;
}

// ---------------- clustering pass: 4 threads per point ----------------
__global__ __launch_bounds__(256)
void cluster_pass(const float* __restrict__ z, const float* __restrict__ t1,
                  const float* __restrict__ clusters,
                  float* __restrict__ D, float* __restrict__ ROWSUM,
                  float* __restrict__ pred_out, float* __restrict__ u_acc,
                  int* __restrict__ cnt, double* __restrict__ S_acc)
{
    __shared__ float cl[KCL*33];
    __shared__ float u_s[KCL];
    __shared__ float swave[4];
    const int tid = threadIdx.x;
    const int lane = tid & 63;
    for (int i = tid; i < KCL*NZ_DIM; i += 256) cl[(i >> 5)*33 + (i & 31)] = clusters[i];
    if (tid < KCL) u_s[tid] = 0.0f;
    __syncthreads();

    const int p  = (blockIdx.x*256 + tid) >> 2;
    const int kg = tid & 3;

    float zr[NZ_DIM];
    const float a = t1[p*3+0]*0.01f, b = t1[p*3+1]*0.01f, c = t1[p*3+2]*0.01f;
    const float cm = a*b*c*0.99f + 1.0f;
    float mean = 0.0f;
    #pragma unroll
    for (int i = 0; i < NZ_DIM; ++i) { zr[i] = z[(size_t)p*NZ_DIM+i]*cm; mean += zr[i]; }
    mean *= (1.0f/NZ_DIM);
    float var = 0.0f;
    #pragma unroll
    for (int i = 0; i < NZ_DIM; ++i) { float d = zr[i]-mean; var += d*d; }
    const float istd = 1.0f / sqrtf(var * (1.0f/(NZ_DIM-1)));
    #pragma unroll
    for (int i = 0; i < NZ_DIM; ++i) zr[i] = (zr[i]-mean)*istd;

    float vals[25];
    float rowsum = 0.0f, best = -1.0f; int bk = 0;
    #pragma unroll
    for (int j = 0; j < 25; ++j) {
        const int k = kg + 4*j;
        float d = 0.0f;
        #pragma unroll
        for (int i = 0; i < NZ_DIM; ++i) { float t = zr[i]-cl[k*33+i]; d = fmaf(t,t,d); }
        float val = 1e-5f + d;
        vals[j] = val;
        rowsum += val;
        if (val > best) { best = val; bk = k; }
        D[(size_t)p*KCL + k] = val;
    }
    rowsum += __shfl_xor(rowsum, 1);
    rowsum += __shfl_xor(rowsum, 2);
    #pragma unroll
    for (int m = 1; m <= 2; m <<= 1) {
        float ov = __shfl_xor(best, m);
        int   ok = __shfl_xor(bk, m);
        if (ov > best || (ov == best && ok < bk)) { best = ov; bk = ok; }
    }
    if (kg == 0) {
        pred_out[p] = (float)bk;
        atomicAdd(&cnt[bk], 1);
        ROWSUM[p] = rowsum;
    }

    const float inv_rs = 1.0f/rowsum;
    float Sp = 0.0f;
    #pragma unroll
    for (int j = 0; j < 25; ++j) {
        float qv = vals[j]*inv_rs;
        float lq = logf(qv);
        float om = 1.0f - qv;
        Sp += sqrtf(-1.0f/(om*om*lq*(float)M_PTS));
        float qs = qv;
        qs += __shfl_xor(qs, 4);
        qs += __shfl_xor(qs, 8);
        qs += __shfl_xor(qs, 16);
        qs += __shfl_xor(qs, 32);
        if (lane < 4) atomicAdd(&u_s[lane + 4*j], qs);
    }
    for (int off = 32; off > 0; off >>= 1) Sp += __shfl_down(Sp, off, 64);
    if (lane == 0) swave[tid >> 6] = Sp;
    __syncthreads();
    if (tid < KCL) atomicAdd(&u_acc[tid], u_s[tid]);
    if (tid == 0) atomicAdd(S_acc, (double)(swave[0]+swave[1]+swave[2]+swave[3]));
}

// ---------------- block reduction helpers ----------------
__device__ __forceinline__ float blk_sum(float v, float* sh) {
    int tid = threadIdx.x;
    sh[tid] = v; __syncthreads();
    for (int s = 128; s > 0; s >>= 1) { if (tid < s) sh[tid] += sh[tid+s]; __syncthreads(); }
    float r = sh[0]; __syncthreads();
    return r;
}
__device__ __forceinline__ float blk_min(float v, float* sh) {
    int tid = threadIdx.x;
    sh[tid] = v; __syncthreads();
    for (int s = 128; s > 0; s >>= 1) { if (tid < s) sh[tid] = fminf(sh[tid], sh[tid+s]); __syncthreads(); }
    float r = sh[0]; __syncthreads();
    return r;
}

// ---------------- finalize u, v, f and u_loss ----------------
__global__ __launch_bounds__(256)
void finalize_kernel(const float* __restrict__ u_in, const int* __restrict__ cnt,
                     const double* __restrict__ dbl, const float* __restrict__ clusters,
                     float* __restrict__ f_out, double* __restrict__ dbl_out)
{
    __shared__ float sh[256];
    __shared__ double shd[256];
    const int tid = threadIdx.x;
    const bool act = (tid < KCL);
    const float S = (float)dbl[0];

    float uv = act ? u_in[tid] : 0.0f;
    float um = blk_sum(uv, sh) * (1.0f/KCL);
    float ud = act ? (uv - um) : 0.0f;
    float uvar = blk_sum(ud*ud, sh) * (1.0f/(KCL-1));
    float un = ud / sqrtf(uvar);
    float umin = blk_min(act ? un : 3.0e38f, sh);
    float ufin = un - umin + 0.001f;

    float vv = 0.0f;
    if (act) { int cc = cnt[tid]; if (cc < 1) cc = 1; vv = sqrtf((float)cc) * S; }
    float vm = blk_sum(vv, sh) * (1.0f/KCL);
    float vd = act ? (vv - vm) : 0.0f;
    float vvar = blk_sum(vd*vd, sh) * (1.0f/(KCL-1));
    float vn = vd / sqrtf(vvar);
    float vmin = blk_min(act ? vn : 3.0e38f, sh);
    float vfin = vn - vmin + 0.001f;

    if (act) f_out[tid] = ufin + vfin + 1.0f;

    double dp = 0.0;
    for (int pair = tid; pair < KCL*KCL; pair += 256) {
        int i = pair / KCL, j = pair % KCL;
        float d = 0.0f;
        #pragma unroll
        for (int t2 = 0; t2 < NZ_DIM; ++t2) {
            float x = clusters[i*NZ_DIM+t2] - clusters[j*NZ_DIM+t2];
            d = fmaf(x, x, d);
        }
        dp += (double)d;
    }
    shd[tid] = dp; __syncthreads();
    for (int s = 128; s > 0; s >>= 1) { if (tid < s) shd[tid] += shd[tid+s]; __syncthreads(); }
    if (tid == 0) {
        dbl_out[3] = 0.01 * (double)(KCL*KCL - KCL) / shd[0];
    }
}

// ---------------- KL pass ----------------
__global__ __launch_bounds__(256)
void kl_pass(const float* __restrict__ D, const float* __restrict__ ROWSUM,
             const float* __restrict__ f, double* __restrict__ kl_acc)
{
    __shared__ float fs[KCL], lfs[KCL];
    __shared__ float swave[4];
    const int tid = threadIdx.x;
    const int lane = tid & 63;
    if (tid < KCL) { float fv = f[tid]; fs[tid] = fv; lfs[tid] = logf(fv); }
    __syncthreads();

    const int p  = (blockIdx.x*256 + tid) >> 2;
    const int kg = tid & 3;

    float vals[25];
    #pragma unroll
    for (int j = 0; j < 25; ++j) vals[j] = D[(size_t)p*KCL + kg + 4*j];

    float sv = 0.0f;
    #pragma unroll
    for (int j = 0; j < 25; ++j) { float v = vals[j]; sv += v*v/fs[kg + 4*j]; }
    sv += __shfl_xor(sv, 1);
    sv += __shfl_xor(sv, 2);

    const float rowsum = ROWSUM[p];
    const float lrs = logf(rowsum), lsv = logf(sv);
    const float inv_sv = 1.0f/sv;
    float klp = 0.0f;
    #pragma unroll
    for (int j = 0; j < 25; ++j) {
        const int k = kg + 4*j;
        float v = vals[j];
        float pv = v*v/fs[k]*inv_sv;
        klp += pv*(logf(v) - lfs[k] - lsv + lrs);
    }
    for (int off = 32; off > 0; off >>= 1) klp += __shfl_down(klp, off, 64);
    if (lane == 0) swave[tid >> 6] = klp;
    __syncthreads();
    if (tid == 0) atomicAdd(kl_acc, (double)(swave[0]+swave[1]+swave[2]+swave[3]));
}

// ---------------- final loss ----------------
__global__ void final_loss(const double* __restrict__ dbl, float* __restrict__ out)
{
    double kl = dbl[1] / (double)((size_t)M_PTS*KCL) * 0.01;
    double re = dbl[2] / (double)((size_t)M_PTS*1024);
    out[0] = (float)(kl + re + dbl[3]);
}

extern "C" void kernel_launch(void* const* d_in, const int* in_sizes, int n_in,
                              void* d_out, int out_size, void* d_ws, size_t ws_size,
                              hipStream_t stream)
{
    const float* x   = (const float*)d_in[0];
    const float* t1c = (const float*)d_in[1];
    const float* clu = (const float*)d_in[2];
    const float* We1 = (const float*)d_in[3];  const float* be1 = (const float*)d_in[4];
    const float* We2 = (const float*)d_in[5];  const float* be2 = (const float*)d_in[6];
    const float* We3 = (const float*)d_in[7];  const float* be3 = (const float*)d_in[8];
    const float* Wz  = (const float*)d_in[9];  const float* bz  = (const float*)d_in[10];
    const float* Wd1 = (const float*)d_in[11]; const float* bd1 = (const float*)d_in[12];
    const float* Wd2 = (const float*)d_in[13]; const float* bd2 = (const float*)d_in[14];
    const float* Wd3 = (const float*)d_in[15]; const float* bd3 = (const float*)d_in[16];
    const float* Wxb = (const float*)d_in[17]; const float* bxb = (const float*)d_in[18];
    float* out = (float*)d_out;

    const size_t M = M_PTS;
    _Float16* H = (_Float16*)d_ws;
    size_t o = 0;
    _Float16* BIGh = H + o; o += M*2048;   // h3 -> d1
    _Float16* BIGl = H + o; o += M*2048;
    _Float16* S1h  = H + o; o += M*512;    // h1 -> d2 ; then D overlay
    _Float16* S1l  = H + o; o += M*512;
    _Float16* S2h  = H + o; o += M*512;    // h2 -> d3 ; then ROWSUM overlay
    _Float16* S2l  = H + o; o += M*512;
    _Float16* Zh   = H + o; o += M*32;
    _Float16* Zl   = H + o; o += M*32;
    // weight planes
    _Float16* We1h = H + o; o += 512*1024; _Float16* We1l = H + o; o += 512*1024;
    _Float16* We2h = H + o; o += 512*512;  _Float16* We2l = H + o; o += 512*512;
    _Float16* We3h = H + o; o += 2048*512; _Float16* We3l = H + o; o += 2048*512;
    _Float16* Wzh  = H + o; o += 32*2048;  _Float16* Wzl  = H + o; o += 32*2048;
    _Float16* Wd1h = H + o; o += 2048*32;  _Float16* Wd1l = H + o; o += 2048*32;
    _Float16* Wd2h = H + o; o += 512*2048; _Float16* Wd2l = H + o; o += 512*2048;
    _Float16* Wd3h = H + o; o += 512*512;  _Float16* Wd3l = H + o; o += 512*512;
    _Float16* Wxbh = H + o; o += 1024*512; _Float16* Wxbl = H + o; o += 1024*512;
    float* fpr = (float*)(H + o);
    float* Zf  = fpr;        fpr += M*32;
    float* U   = fpr;        fpr += 128;
    float* F   = fpr;        fpr += 128;
    int*   CNT = (int*)fpr;  fpr += 128;
    double* DBL = (double*)(((uintptr_t)fpr + 15) & ~(uintptr_t)15);

    // x planes overlay BIG (x dead after L1; BIG first written at L3)
    _Float16* Xh = BIGh;
    _Float16* Xl = BIGh + M*1024;
    // D/ROWSUM overlay S1h/S2h (dead after L7; cluster runs after L7)
    float* Dm  = (float*)S1h;
    float* RSm = (float*)S2h;

    zero_acc<<<1, 256, 0, stream>>>(U, CNT, DBL);

    split_x_kernel<<<(int)(M*1024/4/256), 256, 0, stream>>>(x, Xh, Xl);
    transpose_split<<<dim3(512/32, 1024/32), 256, 0, stream>>>(We1, We1h, We1l, 1024, 512);
    transpose_split<<<dim3(512/32,  512/32), 256, 0, stream>>>(We2, We2h, We2l,  512, 512);
    transpose_split<<<dim3(2048/32, 512/32), 256, 0, stream>>>(We3, We3h, We3l,  512, 2048);
    transpose_split<<<dim3(1,     2048/32),  256, 0, stream>>>(Wz,  Wzh,  Wzl,  2048, 32);
    transpose_split<<<dim3(2048/32, 1),      256, 0, stream>>>(Wd1, Wd1h, Wd1l,   32, 2048);
    transpose_split<<<dim3(512/32, 2048/32), 256, 0, stream>>>(Wd2, Wd2h, Wd2l, 2048, 512);
    transpose_split<<<dim3(512/32,  512/32), 256, 0, stream>>>(Wd3, Wd3h, Wd3l,  512, 512);
    transpose_split<<<dim3(1024/32, 512/32), 256, 0, stream>>>(Wxb, Wxbh, Wxbl,  512, 1024);

    const int MB = M_PTS/128;  // 232
    gemm_sp<2,2,4,4,true ,0><<<dim3(4,  MB), 256, 0, stream>>>(Xh,  Xl,  We1h, We1l, be1, S1h, S1l, nullptr, nullptr, nullptr, M, 512,  1024);
    gemm_sp<2,2,4,4,true ,0><<<dim3(4,  MB), 256, 0, stream>>>(S1h, S1l, We2h, We2l, be2, S2h, S2l, nullptr, nullptr, nullptr, M, 512,  512);
    gemm_sp<2,2,4,4,true ,0><<<dim3(16, MB), 256, 0, stream>>>(S2h, S2l, We3h, We3l, be3, BIGh,BIGl,nullptr, nullptr, nullptr, M, 2048, 512);
    gemm_sp<4,1,2,2,false,1><<<dim3(1,  MB), 256, 0, stream>>>(BIGh,BIGl,Wzh,  Wzl,  bz,  Zh,  Zl,  Zf,      nullptr, nullptr, M, 32,   2048);
    gemm_sp<2,2,4,4,true ,0><<<dim3(16, MB), 256, 0, stream>>>(Zh,  Zl,  Wd1h, Wd1l, bd1, BIGh,BIGl,nullptr, nullptr, nullptr, M, 2048, 32);
    gemm_sp<2,2,4,4,true ,0><<<dim3(4,  MB), 256, 0, stream>>>(BIGh,BIGl,Wd2h, Wd2l, bd2, S1h, S1l, nullptr, nullptr, nullptr, M, 512,  2048);
    gemm_sp<2,2,4,4,true ,0><<<dim3(4,  MB), 256, 0, stream>>>(S1h, S1l, Wd3h, Wd3l, bd3, S2h, S2l, nullptr, nullptr, nullptr, M, 512,  512);
    gemm_sp<2,2,4,4,false,2><<<dim3(8,  MB), 256, 0, stream>>>(S2h, S2l, Wxbh, Wxbl, bxb, nullptr,nullptr,nullptr, x,  DBL+2,  M, 1024, 512);

    const int PB = (M_PTS*4)/256;   // 464 blocks, 4 threads/point
    cluster_pass<<<PB, 256, 0, stream>>>(Zf, t1c, clu, Dm, RSm, out, U, CNT, DBL + 0);
    finalize_kernel<<<1, 256, 0, stream>>>(U, CNT, DBL, clu, F, DBL);
    kl_pass<<<PB, 256, 0, stream>>>(Dm, RSm, F, DBL + 1);
    final_loss<<<1, 1, 0, stream>>>(DBL, out + M_PTS);
}

// Round 5
// 1357.018 us; speedup vs baseline: 1.3244x; 1.3244x over previous
//
#include <hip/hip_runtime.h>
#include <math.h>

#define M_PTS 29696
#define KCL 100
#define NZ_DIM 32

typedef _Float16 h8 __attribute__((ext_vector_type(8)));
typedef _Float16 h4 __attribute__((ext_vector_type(4)));
typedef float f4 __attribute__((ext_vector_type(4)));

// async global->LDS, 16B per lane; LDS dest is wave-uniform base + lane*16
__device__ __forceinline__ void load_lds16(const void* g, void* l) {
    __builtin_amdgcn_global_load_lds(
        (const __attribute__((address_space(1))) void*)g,
        (__attribute__((address_space(3))) void*)l, 16, 0, 0);
}

// ---------------- weight transpose+split: W (KxN) fp32 -> WTh/WTl (NxK) f16 ----------------
__global__ __launch_bounds__(256)
void transpose_split(const float* __restrict__ W, _Float16* __restrict__ WTh,
                     _Float16* __restrict__ WTl, int K, int N)
{
    __shared__ float t[32][33];
    const int tid = threadIdx.x;
    const int n0 = blockIdx.x * 32, k0 = blockIdx.y * 32;
    {
        int r = tid / 8, c = (tid % 8) * 4;
        const float4 v = *(const float4*)(W + (size_t)(k0 + r) * N + n0 + c);
        t[r][c+0] = v.x; t[r][c+1] = v.y; t[r][c+2] = v.z; t[r][c+3] = v.w;
    }
    __syncthreads();
    {
        int r = tid / 8, c = (tid % 8) * 4;   // r = n idx, c = k idx
        h4 hi, lo;
        #pragma unroll
        for (int u = 0; u < 4; ++u) {
            float f = t[c+u][r];
            _Float16 h = (_Float16)f;
            hi[u] = h; lo[u] = (_Float16)(f - (float)h);
        }
        *(h4*)(WTh + (size_t)(n0 + r) * K + k0 + c) = hi;
        *(h4*)(WTl + (size_t)(n0 + r) * K + k0 + c) = lo;
    }
}

// ---------------- x split: fp32 -> hi/lo f16 planes ----------------
__global__ __launch_bounds__(256)
void split_x_kernel(const float* __restrict__ x, _Float16* __restrict__ Xh,
                    _Float16* __restrict__ Xl)
{
    const size_t i = ((size_t)blockIdx.x*256 + threadIdx.x)*4;
    const float4 v = *(const float4*)(x + i);
    float vv[4] = {v.x, v.y, v.z, v.w};
    h4 hi, lo;
    #pragma unroll
    for (int u = 0; u < 4; ++u) {
        _Float16 h = (_Float16)vv[u];
        hi[u] = h; lo[u] = (_Float16)(vv[u] - (float)h);
    }
    *(h4*)(Xh + i) = hi;
    *(h4*)(Xl + i) = lo;
}

// ---------------- MFMA GEMM, async double-buffered LDS ----------------
// A planes: MxK f16; B planes: NxK f16. C = act(A@B^T + bias).
// TERMS=3: split-precision (hi*hi + hi*lo + lo*hi), PL=2 planes staged.
// TERMS=1: plain f16, PL=1.
// MODE 0: write hi+lo. MODE 1: hi + fp32. MODE 2: fused re-loss. MODE 3: hi only.
template<int WM,int WN,int TM,int TN,bool RELU,int MODE,int TERMS>
__global__ __launch_bounds__(WM*WN*64)
void gemm_sp(const _Float16* __restrict__ Ahp, const _Float16* __restrict__ Alp,
             const _Float16* __restrict__ Bhp, const _Float16* __restrict__ Blp,
             const float* __restrict__ bias,
             _Float16* __restrict__ Ch, _Float16* __restrict__ Cl,
             float* __restrict__ Cf, const float* __restrict__ Xref,
             double* __restrict__ loss_acc,
             int M, int N, int K)
{
    constexpr int BM = WM*TM*16, BN = WN*TN*16, NW = WM*WN;
    constexpr int PL = (TERMS == 3) ? 2 : 1;
    constexpr int CA = BM/16, CB = BN/16;          // 1KB chunks
    constexpr int STRIDE = PL*(BM+BN)*32;          // halves per stage
    // per-wave async issues per stage (uniform across waves by construction)
    constexpr int NPW = (CA/NW)*PL + ((CB >= NW) ? (CB/NW) : 1)*PL;
    __shared__ __align__(16) _Float16 smem[2*STRIDE];

    const int tid = threadIdx.x;
    const int wave = tid >> 6, lane = tid & 63;
    const int wm = wave / WN, wn = wave % WN;
    const int lrow = lane & 15, lq = lane >> 4;
    const int sw = (lrow >> 1) & 3;                // bank swizzle
    const int lr4 = lane >> 2, lc4 = lane & 3;     // staging row-in-chunk / 16B col
    const int bm0 = blockIdx.y * BM, bn0 = blockIdx.x * BN;

    f4 acc[TM][TN];
    #pragma unroll
    for (int i = 0; i < TM; ++i)
        #pragma unroll
        for (int j = 0; j < TN; ++j)
            acc[i][j] = (f4)0.0f;

    auto stage = [&](int s, int k0) {
        _Float16* base = smem + s*STRIDE;
        #pragma unroll
        for (int c = wave; c < CA; c += NW) {
            int r = c*16 + lr4;
            int g = lc4 ^ ((r >> 1) & 3);
            size_t goff = (size_t)(bm0 + r)*K + k0 + g*8;
            load_lds16(Ahp + goff, base + c*512);
            if (PL == 2) load_lds16(Alp + goff, base + BM*32 + c*512);
        }
        if (CB >= NW) {
            #pragma unroll
            for (int c = wave; c < CB; c += NW) {
                int r = c*16 + lr4;
                int g = lc4 ^ ((r >> 1) & 3);
                size_t goff = (size_t)(bn0 + r)*K + k0 + g*8;
                load_lds16(Bhp + goff, base + PL*BM*32 + c*512);
                if (PL == 2) load_lds16(Blp + goff, base + PL*BM*32 + BN*32 + c*512);
            }
        } else {  // fewer B chunks than waves: duplicate issues keep counts uniform
            int c = wave % CB;
            int r = c*16 + lr4;
            int g = lc4 ^ ((r >> 1) & 3);
            size_t goff = (size_t)(bn0 + r)*K + k0 + g*8;
            load_lds16(Bhp + goff, base + PL*BM*32 + c*512);
            if (PL == 2) load_lds16(Blp + goff, base + PL*BM*32 + BN*32 + c*512);
        }
    };

    stage(0, 0);
    const int steps = K >> 5;
    for (int i = 0; i < steps; ++i) {
        const int sel = i & 1;
        if (i + 1 < steps) {
            stage(sel ^ 1, (i + 1) << 5);                 // prefetch next stage
            __builtin_amdgcn_s_waitcnt(0x0F70 | NPW);     // drain current stage only
        } else {
            __builtin_amdgcn_s_waitcnt(0x0F70);
        }
        __builtin_amdgcn_s_barrier();                     // all waves' data visible

        const _Float16* base = smem + sel*STRIDE;
        h8 ah[TM], al[TM], bh[TN], bl[TN];
        #pragma unroll
        for (int i2 = 0; i2 < TM; ++i2) {
            int row = (wm*TM + i2)*16 + lrow;
            int off = row*32 + ((lq ^ sw)*8);
            ah[i2] = *(const h8*)(base + off);
            if (PL == 2) al[i2] = *(const h8*)(base + BM*32 + off);
        }
        #pragma unroll
        for (int j = 0; j < TN; ++j) {
            int row = (wn*TN + j)*16 + lrow;
            int off = row*32 + ((lq ^ sw)*8);
            bh[j] = *(const h8*)(base + PL*BM*32 + off);
            if (PL == 2) bl[j] = *(const h8*)(base + PL*BM*32 + BN*32 + off);
        }
        #pragma unroll
        for (int i2 = 0; i2 < TM; ++i2)
            #pragma unroll
            for (int j = 0; j < TN; ++j)
                acc[i2][j] = __builtin_amdgcn_mfma_f32_16x16x32_f16(ah[i2], bh[j], acc[i2][j], 0, 0, 0);
        if (TERMS == 3) {
            #pragma unroll
            for (int i2 = 0; i2 < TM; ++i2)
                #pragma unroll
                for (int j = 0; j < TN; ++j)
                    acc[i2][j] = __builtin_amdgcn_mfma_f32_16x16x32_f16(ah[i2], bl[j], acc[i2][j], 0, 0, 0);
            #pragma unroll
            for (int i2 = 0; i2 < TM; ++i2)
                #pragma unroll
                for (int j = 0; j < TN; ++j)
                    acc[i2][j] = __builtin_amdgcn_mfma_f32_16x16x32_f16(al[i2], bh[j], acc[i2][j], 0, 0, 0);
        }
        __builtin_amdgcn_s_barrier();   // buffer consumed; next iter may prefetch into it
    }

    // ---- epilogue ----
    float lsum = 0.0f;
    #pragma unroll
    for (int j = 0; j < TN; ++j) {
        int col = bn0 + (wn*TN + j)*16 + lrow;
        float bj = bias[col];
        #pragma unroll
        for (int i = 0; i < TM; ++i) {
            int rbase = bm0 + (wm*TM + i)*16 + lq*4;
            #pragma unroll
            for (int r = 0; r < 4; ++r) {
                float v = acc[i][j][r] + bj;
                if (RELU) v = fmaxf(v, 0.0f);
                size_t idx = (size_t)(rbase + r)*N + col;
                if (MODE == 2) {
                    float d = v - Xref[idx];
                    lsum = fmaf(d, d, lsum);
                } else if (MODE == 0) {
                    _Float16 hh = (_Float16)v;
                    __builtin_nontemporal_store(hh, &Ch[idx]);
                    __builtin_nontemporal_store((_Float16)(v - (float)hh), &Cl[idx]);
                } else if (MODE == 1) {
                    _Float16 hh = (_Float16)v;
                    __builtin_nontemporal_store(hh, &Ch[idx]);
                    __builtin_nontemporal_store(v, &Cf[idx]);
                } else {
                    __builtin_nontemporal_store((_Float16)v, &Ch[idx]);
                }
            }
        }
    }
    if (MODE == 2) {
        for (int off = 32; off > 0; off >>= 1) lsum += __shfl_down(lsum, off, 64);
        __syncthreads();
        float* sc = (float*)smem;
        if (lane == 0) sc[wave] = lsum;
        __syncthreads();
        if (tid == 0) {
            double t = 0.0;
            for (int w = 0; w < NW; ++w) t += (double)sc[w];
            atomicAdd(loss_acc, t);
        }
    }
}

// ---------------- accumulator zeroing ----------------
__global__ void zero_acc(float* __restrict__ u, int* __restrict__ cnt, double* __restrict__ dbl)
{
    int t = threadIdx.x;
    if (t < KCL) { u[t] = 0.0f; cnt[t] = 0; }
    if (t < 8) dbl[t] = 0.0;
}

// ---------------- clustering pass: 4 threads per point ----------------
__global__ __launch_bounds__(256)
void cluster_pass(const float* __restrict__ z, const float* __restrict__ t1,
                  const float* __restrict__ clusters,
                  float* __restrict__ D, float* __restrict__ ROWSUM,
                  float* __restrict__ pred_out, float* __restrict__ u_acc,
                  int* __restrict__ cnt, double* __restrict__ S_acc)
{
    __shared__ float cl[KCL*33];
    __shared__ float u_s[KCL];
    __shared__ float swave[4];
    const int tid = threadIdx.x;
    const int lane = tid & 63;
    for (int i = tid; i < KCL*NZ_DIM; i += 256) cl[(i >> 5)*33 + (i & 31)] = clusters[i];
    if (tid < KCL) u_s[tid] = 0.0f;
    __syncthreads();

    const int p  = (blockIdx.x*256 + tid) >> 2;
    const int kg = tid & 3;

    float zr[NZ_DIM];
    const float a = t1[p*3+0]*0.01f, b = t1[p*3+1]*0.01f, c = t1[p*3+2]*0.01f;
    const float cm = a*b*c*0.99f + 1.0f;
    float mean = 0.0f;
    #pragma unroll
    for (int i = 0; i < NZ_DIM; ++i) { zr[i] = z[(size_t)p*NZ_DIM+i]*cm; mean += zr[i]; }
    mean *= (1.0f/NZ_DIM);
    float var = 0.0f;
    #pragma unroll
    for (int i = 0; i < NZ_DIM; ++i) { float d = zr[i]-mean; var += d*d; }
    const float istd = 1.0f / sqrtf(var * (1.0f/(NZ_DIM-1)));
    #pragma unroll
    for (int i = 0; i < NZ_DIM; ++i) zr[i] = (zr[i]-mean)*istd;

    float vals[25];
    float rowsum = 0.0f, best = -1.0f; int bk = 0;
    #pragma unroll
    for (int j = 0; j < 25; ++j) {
        const int k = kg + 4*j;
        float d = 0.0f;
        #pragma unroll
        for (int i = 0; i < NZ_DIM; ++i) { float t = zr[i]-cl[k*33+i]; d = fmaf(t,t,d); }
        float val = 1e-5f + d;
        vals[j] = val;
        rowsum += val;
        if (val > best) { best = val; bk = k; }
        D[(size_t)p*KCL + k] = val;
    }
    rowsum += __shfl_xor(rowsum, 1);
    rowsum += __shfl_xor(rowsum, 2);
    #pragma unroll
    for (int m = 1; m <= 2; m <<= 1) {
        float ov = __shfl_xor(best, m);
        int   ok = __shfl_xor(bk, m);
        if (ov > best || (ov == best && ok < bk)) { best = ov; bk = ok; }
    }
    if (kg == 0) {
        pred_out[p] = (float)bk;
        atomicAdd(&cnt[bk], 1);
        ROWSUM[p] = rowsum;
    }

    const float inv_rs = 1.0f/rowsum;
    float Sp = 0.0f;
    #pragma unroll
    for (int j = 0; j < 25; ++j) {
        float qv = vals[j]*inv_rs;
        float lq = logf(qv);
        float om = 1.0f - qv;
        Sp += sqrtf(-1.0f/(om*om*lq*(float)M_PTS));
        float qs = qv;
        qs += __shfl_xor(qs, 4);
        qs += __shfl_xor(qs, 8);
        qs += __shfl_xor(qs, 16);
        qs += __shfl_xor(qs, 32);
        if (lane < 4) atomicAdd(&u_s[lane + 4*j], qs);
    }
    for (int off = 32; off > 0; off >>= 1) Sp += __shfl_down(Sp, off, 64);
    if (lane == 0) swave[tid >> 6] = Sp;
    __syncthreads();
    if (tid < KCL) atomicAdd(&u_acc[tid], u_s[tid]);
    if (tid == 0) atomicAdd(S_acc, (double)(swave[0]+swave[1]+swave[2]+swave[3]));
}

// ---------------- block reduction helpers ----------------
__device__ __forceinline__ float blk_sum(float v, float* sh) {
    int tid = threadIdx.x;
    sh[tid] = v; __syncthreads();
    for (int s = 128; s > 0; s >>= 1) { if (tid < s) sh[tid] += sh[tid+s]; __syncthreads(); }
    float r = sh[0]; __syncthreads();
    return r;
}
__device__ __forceinline__ float blk_min(float v, float* sh) {
    int tid = threadIdx.x;
    sh[tid] = v; __syncthreads();
    for (int s = 128; s > 0; s >>= 1) { if (tid < s) sh[tid] = fminf(sh[tid], sh[tid+s]); __syncthreads(); }
    float r = sh[0]; __syncthreads();
    return r;
}

// ---------------- finalize u, v, f and u_loss ----------------
__global__ __launch_bounds__(256)
void finalize_kernel(const float* __restrict__ u_in, const int* __restrict__ cnt,
                     const double* __restrict__ dbl, const float* __restrict__ clusters,
                     float* __restrict__ f_out, double* __restrict__ dbl_out)
{
    __shared__ float sh[256];
    __shared__ double shd[256];
    const int tid = threadIdx.x;
    const bool act = (tid < KCL);
    const float S = (float)dbl[0];

    float uv = act ? u_in[tid] : 0.0f;
    float um = blk_sum(uv, sh) * (1.0f/KCL);
    float ud = act ? (uv - um) : 0.0f;
    float uvar = blk_sum(ud*ud, sh) * (1.0f/(KCL-1));
    float un = ud / sqrtf(uvar);
    float umin = blk_min(act ? un : 3.0e38f, sh);
    float ufin = un - umin + 0.001f;

    float vv = 0.0f;
    if (act) { int cc = cnt[tid]; if (cc < 1) cc = 1; vv = sqrtf((float)cc) * S; }
    float vm = blk_sum(vv, sh) * (1.0f/KCL);
    float vd = act ? (vv - vm) : 0.0f;
    float vvar = blk_sum(vd*vd, sh) * (1.0f/(KCL-1));
    float vn = vd / sqrtf(vvar);
    float vmin = blk_min(act ? vn : 3.0e38f, sh);
    float vfin = vn - vmin + 0.001f;

    if (act) f_out[tid] = ufin + vfin + 1.0f;

    double dp = 0.0;
    for (int pair = tid; pair < KCL*KCL; pair += 256) {
        int i = pair / KCL, j = pair % KCL;
        float d = 0.0f;
        #pragma unroll
        for (int t2 = 0; t2 < NZ_DIM; ++t2) {
            float x = clusters[i*NZ_DIM+t2] - clusters[j*NZ_DIM+t2];
            d = fmaf(x, x, d);
        }
        dp += (double)d;
    }
    shd[tid] = dp; __syncthreads();
    for (int s = 128; s > 0; s >>= 1) { if (tid < s) shd[tid] += shd[tid+s]; __syncthreads(); }
    if (tid == 0) {
        dbl_out[3] = 0.01 * (double)(KCL*KCL - KCL) / shd[0];
    }
}

// ---------------- KL pass ----------------
__global__ __launch_bounds__(256)
void kl_pass(const float* __restrict__ D, const float* __restrict__ ROWSUM,
             const float* __restrict__ f, double* __restrict__ kl_acc)
{
    __shared__ float fs[KCL], lfs[KCL];
    __shared__ float swave[4];
    const int tid = threadIdx.x;
    const int lane = tid & 63;
    if (tid < KCL) { float fv = f[tid]; fs[tid] = fv; lfs[tid] = logf(fv); }
    __syncthreads();

    const int p  = (blockIdx.x*256 + tid) >> 2;
    const int kg = tid & 3;

    float vals[25];
    #pragma unroll
    for (int j = 0; j < 25; ++j) vals[j] = D[(size_t)p*KCL + kg + 4*j];

    float sv = 0.0f;
    #pragma unroll
    for (int j = 0; j < 25; ++j) { float v = vals[j]; sv += v*v/fs[kg + 4*j]; }
    sv += __shfl_xor(sv, 1);
    sv += __shfl_xor(sv, 2);

    const float rowsum = ROWSUM[p];
    const float lrs = logf(rowsum), lsv = logf(sv);
    const float inv_sv = 1.0f/sv;
    float klp = 0.0f;
    #pragma unroll
    for (int j = 0; j < 25; ++j) {
        const int k = kg + 4*j;
        float v = vals[j];
        float pv = v*v/fs[k]*inv_sv;
        klp += pv*(logf(v) - lfs[k] - lsv + lrs);
    }
    for (int off = 32; off > 0; off >>= 1) klp += __shfl_down(klp, off, 64);
    if (lane == 0) swave[tid >> 6] = klp;
    __syncthreads();
    if (tid == 0) atomicAdd(kl_acc, (double)(swave[0]+swave[1]+swave[2]+swave[3]));
}

// ---------------- final loss ----------------
__global__ void final_loss(const double* __restrict__ dbl, float* __restrict__ out)
{
    double kl = dbl[1] / (double)((size_t)M_PTS*KCL) * 0.01;
    double re = dbl[2] / (double)((size_t)M_PTS*1024);
    out[0] = (float)(kl + re + dbl[3]);
}

extern "C" void kernel_launch(void* const* d_in, const int* in_sizes, int n_in,
                              void* d_out, int out_size, void* d_ws, size_t ws_size,
                              hipStream_t stream)
{
    const float* x   = (const float*)d_in[0];
    const float* t1c = (const float*)d_in[1];
    const float* clu = (const float*)d_in[2];
    const float* We1 = (const float*)d_in[3];  const float* be1 = (const float*)d_in[4];
    const float* We2 = (const float*)d_in[5];  const float* be2 = (const float*)d_in[6];
    const float* We3 = (const float*)d_in[7];  const float* be3 = (const float*)d_in[8];
    const float* Wz  = (const float*)d_in[9];  const float* bz  = (const float*)d_in[10];
    const float* Wd1 = (const float*)d_in[11]; const float* bd1 = (const float*)d_in[12];
    const float* Wd2 = (const float*)d_in[13]; const float* bd2 = (const float*)d_in[14];
    const float* Wd3 = (const float*)d_in[15]; const float* bd3 = (const float*)d_in[16];
    const float* Wxb = (const float*)d_in[17]; const float* bxb = (const float*)d_in[18];
    float* out = (float*)d_out;

    const size_t M = M_PTS;
    _Float16* H = (_Float16*)d_ws;
    size_t o = 0;
    _Float16* BIGh = H + o; o += M*2048;   // h3 -> d1
    _Float16* BIGl = H + o; o += M*2048;
    _Float16* S1h  = H + o; o += M*512;    // h1 -> d2
    _Float16* S1l  = H + o; o += M*512;    // (dead after h3) -> D overlay
    _Float16* S2h  = H + o; o += M*512;    // h2 -> d3
    _Float16* S2l  = H + o; o += M*512;    // (dead after h3) -> ROWSUM overlay
    _Float16* Zh   = H + o; o += M*32;
    _Float16* Zl   = H + o; o += M*32;     // unused now; kept for layout stability
    _Float16* We1h = H + o; o += 512*1024; _Float16* We1l = H + o; o += 512*1024;
    _Float16* We2h = H + o; o += 512*512;  _Float16* We2l = H + o; o += 512*512;
    _Float16* We3h = H + o; o += 2048*512; _Float16* We3l = H + o; o += 2048*512;
    _Float16* Wzh  = H + o; o += 32*2048;  _Float16* Wzl  = H + o; o += 32*2048;
    _Float16* Wd1h = H + o; o += 2048*32;  _Float16* Wd1l = H + o; o += 2048*32;
    _Float16* Wd2h = H + o; o += 512*2048; _Float16* Wd2l = H + o; o += 512*2048;
    _Float16* Wd3h = H + o; o += 512*512;  _Float16* Wd3l = H + o; o += 512*512;
    _Float16* Wxbh = H + o; o += 1024*512; _Float16* Wxbl = H + o; o += 1024*512;
    float* fpr = (float*)(H + o);
    float* Zf  = fpr;        fpr += M*32;
    float* U   = fpr;        fpr += 128;
    float* F   = fpr;        fpr += 128;
    int*   CNT = (int*)fpr;  fpr += 128;
    double* DBL = (double*)(((uintptr_t)fpr + 15) & ~(uintptr_t)15);

    // x planes overlay BIG (x-planes dead after h1; BIG first written at h3)
    _Float16* Xh = BIGh;
    _Float16* Xl = BIGh + M*1024;
    // D/ROWSUM overlay the dead encoder lo-planes (decoder never touches them)
    float* Dm  = (float*)S1l;
    float* RSm = (float*)S2l;

    zero_acc<<<1, 256, 0, stream>>>(U, CNT, DBL);

    split_x_kernel<<<(int)(M*1024/4/256), 256, 0, stream>>>(x, Xh, Xl);
    transpose_split<<<dim3(512/32, 1024/32), 256, 0, stream>>>(We1, We1h, We1l, 1024, 512);
    transpose_split<<<dim3(512/32,  512/32), 256, 0, stream>>>(We2, We2h, We2l,  512, 512);
    transpose_split<<<dim3(2048/32, 512/32), 256, 0, stream>>>(We3, We3h, We3l,  512, 2048);
    transpose_split<<<dim3(1,     2048/32),  256, 0, stream>>>(Wz,  Wzh,  Wzl,  2048, 32);
    transpose_split<<<dim3(2048/32, 1),      256, 0, stream>>>(Wd1, Wd1h, Wd1l,   32, 2048);
    transpose_split<<<dim3(512/32, 2048/32), 256, 0, stream>>>(Wd2, Wd2h, Wd2l, 2048, 512);
    transpose_split<<<dim3(512/32,  512/32), 256, 0, stream>>>(Wd3, Wd3h, Wd3l,  512, 512);
    transpose_split<<<dim3(1024/32, 512/32), 256, 0, stream>>>(Wxb, Wxbh, Wxbl,  512, 1024);

    const int MB = M_PTS/128;  // 232
    // ---- encoder: f16x3 split precision (argmax-exact path) ----
    gemm_sp<2,2,4,4,true ,0,3><<<dim3(4,  MB), 256, 0, stream>>>(Xh,  Xl,  We1h, We1l, be1, S1h, S1l, nullptr, nullptr, nullptr, M, 512,  1024);
    gemm_sp<2,2,4,4,true ,0,3><<<dim3(4,  MB), 256, 0, stream>>>(S1h, S1l, We2h, We2l, be2, S2h, S2l, nullptr, nullptr, nullptr, M, 512,  512);
    gemm_sp<2,2,4,4,true ,0,3><<<dim3(16, MB), 256, 0, stream>>>(S2h, S2l, We3h, We3l, be3, BIGh,BIGl,nullptr, nullptr, nullptr, M, 2048, 512);
    gemm_sp<4,1,2,2,false,1,3><<<dim3(1,  MB), 256, 0, stream>>>(BIGh,BIGl,Wzh,  Wzl,  bz,  Zh,  nullptr, Zf,  nullptr, nullptr, M, 32,   2048);
    // ---- decoder: plain f16 (feeds re_loss only) ----
    gemm_sp<2,2,4,4,true ,3,1><<<dim3(16, MB), 256, 0, stream>>>(Zh,  nullptr, Wd1h, nullptr, bd1, BIGh, nullptr, nullptr, nullptr, nullptr, M, 2048, 32);
    gemm_sp<2,2,4,4,true ,3,1><<<dim3(4,  MB), 256, 0, stream>>>(BIGh,nullptr, Wd2h, nullptr, bd2, S1h,  nullptr, nullptr, nullptr, nullptr, M, 512,  2048);
    gemm_sp<2,2,4,4,true ,3,1><<<dim3(4,  MB), 256, 0, stream>>>(S1h, nullptr, Wd3h, nullptr, bd3, S2h,  nullptr, nullptr, nullptr, nullptr, M, 512,  512);
    gemm_sp<2,2,4,4,false,2,1><<<dim3(8,  MB), 256, 0, stream>>>(S2h, nullptr, Wxbh, nullptr, bxb, nullptr, nullptr, nullptr, x, DBL+2, M, 1024, 512);

    const int PB = (M_PTS*4)/256;   // 464 blocks, 4 threads/point
    cluster_pass<<<PB, 256, 0, stream>>>(Zf, t1c, clu, Dm, RSm, out, U, CNT, DBL + 0);
    finalize_kernel<<<1, 256, 0, stream>>>(U, CNT, DBL, clu, F, DBL);
    kl_pass<<<PB, 256, 0, stream>>>(Dm, RSm, F, DBL + 1);
    final_loss<<<1, 1, 0, stream>>>(DBL, out + M_PTS);
}